// Round 13
// baseline (287.646 us; speedup 1.0000x reference)
//
#include <hip/hip_runtime.h>

// VQ-VAE vector quantization via bf16-split MFMA.
// Round 13: ABLATION ROUND. Six dispatches of template<MODE> vq_dist_t:
//   M0 full (real)               -> qidx/loss real
//   M1 noMFMA (frags kept live)  -> scratch
//   M2 noLDSread+noMFMA          -> scratch   (staging+sync+VALU)
//   M3 noSync (prestage 4 bufs)  -> scratch   (LDS+MFMA+VALU, no barriers)
//   M4 regB (no LDS, no sync)    -> scratch   (MFMA+VALU only)
// Per-dispatch rocprof rows give the marginal cost of each phase.
// ws layout (floats):
//   [0..31] loss real, [32..63] loss scratch, [1024..2047] nhn,
//   [2048..34815] hist partials, [34816..100351] packed codes (16 x 16KB),
//   [102400..167935] qidx ushort[131072], [169984..235519] scratch qidx

typedef __attribute__((ext_vector_type(8))) short short8;
typedef __attribute__((ext_vector_type(16))) float f32x16;

#define LOSS_OFF 0
#define NHN_OFF 1024
#define PART_OFF 2048
#define PACKED_OFF 34816
#define QIDX_OFF 102400
#define SCR_OFF 169984
#define NPART 32

#define GLL16(gsrc, ldst)                                                      \
  __builtin_amdgcn_global_load_lds(                                            \
      (const __attribute__((address_space(1))) void*)(gsrc),                   \
      (__attribute__((address_space(3))) void*)(ldst), 16, 0, 0)

__device__ __forceinline__ unsigned short bf16_rne(float v, float& rest) {
  const unsigned u = __float_as_uint(v);
  const unsigned r = u + 0x7fffu + ((u >> 16) & 1u);
  const unsigned short h = (unsigned short)(r >> 16);
  rest = v - __uint_as_float((unsigned)h << 16);
  return h;
}

__global__ void vq_pack(const float* __restrict__ cb0, const float* __restrict__ cb1,
                        float* __restrict__ ws) {
  const int c = blockIdx.x * 256 + threadIdx.x;  // 0..1023
  if (c < 64) ws[LOSS_OFF + c] = 0.0f;
#pragma unroll
  for (int p = 0; p < NPART; ++p) ws[PART_OFF + p * 1024 + c] = 0.0f;
  const float* row = (c < 512) ? (cb0 + (size_t)c * 64) : (cb1 + (size_t)(c - 512) * 64);
  float v[64];
  float nrm = 0.f;
#pragma unroll
  for (int d = 0; d < 64; d += 4) {
    const float4 f = *(const float4*)(row + d);
    v[d] = f.x; v[d + 1] = f.y; v[d + 2] = f.z; v[d + 3] = f.w;
    nrm += f.x * f.x + f.y * f.y + f.z * f.z + f.w * f.w;
  }
  ws[NHN_OFF + c] = -0.5f * nrm;
  unsigned short hi[64], lo[64];
#pragma unroll
  for (int d = 0; d < 64; ++d) {
    float rest, dump;
    hi[d] = bf16_rne(v[d], rest);
    lo[d] = bf16_rne(rest, dump);
  }
  float* base = ws + PACKED_OFF + (size_t)(c >> 6) * 4096 + (c & 63) * 4;
#pragma unroll
  for (int g = 0; g < 16; ++g) {
    short8 gr;
#pragma unroll
    for (int e = 0; e < 8; ++e)
      gr[e] = (short)((g < 8) ? hi[g * 8 + e] : lo[(g - 8) * 8 + e]);
    *(short8*)(base + g * 256) = gr;
  }
}

template <int MODE>
__global__ __launch_bounds__(512, 2) void vq_dist_t(
    const float* __restrict__ xin, const int* __restrict__ idxp,
    float* __restrict__ ws) {
  __shared__ char smem[69632];  // 4 x 16KB ring + 4KB nhn
  char* ring = smem;
  float* nhl = (float*)(smem + 65536);
  const int tid = threadIdx.x;
  const int w = tid >> 6;
  const int l = tid & 63;
  const int half = l >> 5;
  const int col = l & 31;
  const int blk = blockIdx.x;  // 256 blocks x 512 q
  const int bb = blk >> 3;
  const int hw0 = (blk & 7) << 9;
  const int nch = (*idxp == 0) ? 8 : 16;
  const char* pk = (const char*)(ws + PACKED_OFF);

  const float nv0 = ws[NHN_OFF + tid];
  const float nv1 = ws[NHN_OFF + 512 + tid];

  short8 xh[2][4], xl[2][4];
  float xx[2];
#pragma unroll
  for (int m = 0; m < 2; ++m) {
    float vv[4][8];
    const float* xb =
        xin + ((size_t)(bb * 64 + half * 8)) * 4096 + hw0 + w * 64 + m * 32 + col;
#pragma unroll
    for (int kf = 0; kf < 4; ++kf)
#pragma unroll
      for (int j = 0; j < 8; ++j)
        vv[kf][j] = xb[((size_t)(kf * 16 + j)) * 4096];
    float s = 0.f;
#pragma unroll
    for (int kf = 0; kf < 4; ++kf)
#pragma unroll
      for (int j = 0; j < 8; ++j) {
        const float v = vv[kf][j];
        float rest, dump;
        xh[m][kf][j] = (short)bf16_rne(v, rest);
        xl[m][kf][j] = (short)bf16_rne(rest, dump);
        s += v * v;
      }
    s += __shfl_xor(s, 32);
    xx[m] = s;
  }
  nhl[tid] = nv0;
  nhl[512 + tid] = nv1;
  asm volatile("s_waitcnt lgkmcnt(0)" ::: "memory");
  asm volatile("s_waitcnt vmcnt(0)" ::: "memory");

  float best[2][16];
#pragma unroll
  for (int m = 0; m < 2; ++m)
#pragma unroll
    for (int r = 0; r < 16; ++r) best[m][r] = -3.4e38f;

  auto stage = [&](int ch, int buf) {
    const char* src = pk + (size_t)ch * 16384 + w * 2048 + l * 16;
    char* dst = ring + buf * 16384 + w * 2048;
    GLL16(src, dst);
    GLL16(src + 1024, dst + 1024);
  };

  if constexpr (MODE == 3) {
    stage(0, 0); stage(1, 1); stage(2, 2); stage(3, 3);
    asm volatile("s_waitcnt vmcnt(0)" ::: "memory");
    __builtin_amdgcn_s_barrier();
  } else if constexpr (MODE != 4) {
    stage(0, 0); stage(1, 1); stage(2, 2);
  }

  for (int i = 0; i < nch; ++i) {
    if constexpr (MODE <= 2) {
      if (i < nch - 2) {
        asm volatile("s_waitcnt vmcnt(4)" ::: "memory");
      } else if (i == nch - 2) {
        asm volatile("s_waitcnt vmcnt(2)" ::: "memory");
      } else {
        asm volatile("s_waitcnt vmcnt(0)" ::: "memory");
      }
      __builtin_amdgcn_s_barrier();
      if (i + 3 < nch) stage(i + 3, (i + 3) & 3);
    }
    const char* bufp = ring + (i & 3) * 16384;
    const int cb = col * 16;
    const float nh0 = nhl[i * 64 + col];
    const float nh1 = nhl[i * 64 + 32 + col];
    f32x16 a00, a01, a10, a11;
#pragma unroll
    for (int r = 0; r < 16; ++r) {
      a00[r] = nh0; a01[r] = nh1; a10[r] = nh0; a11[r] = nh1;
    }
#pragma unroll
    for (int kf = 0; kf < 4; ++kf) {
      if constexpr (MODE <= 1 || MODE == 3) {
        const char* ph = bufp + (2 * kf + half) * 1024 + cb;
        const char* pl = bufp + (8 + 2 * kf + half) * 1024 + cb;
        short8 bh0 = *(const short8*)(ph);
        short8 bh1 = *(const short8*)(ph + 512);
        short8 bl0 = *(const short8*)(pl);
        short8 bl1 = *(const short8*)(pl + 512);
        asm volatile("s_waitcnt lgkmcnt(0)" ::: "memory");
        __builtin_amdgcn_sched_barrier(0);
        if constexpr (MODE == 1) {
          // keep the ds_reads live without consuming them in MFMA
          asm volatile("" :: "v"(bh0), "v"(bh1), "v"(bl0), "v"(bl1));
        } else {
          __builtin_amdgcn_s_setprio(1);
          a00 = __builtin_amdgcn_mfma_f32_32x32x16_bf16(xh[0][kf], bh0, a00, 0, 0, 0);
          a01 = __builtin_amdgcn_mfma_f32_32x32x16_bf16(xh[0][kf], bh1, a01, 0, 0, 0);
          a10 = __builtin_amdgcn_mfma_f32_32x32x16_bf16(xh[1][kf], bh0, a10, 0, 0, 0);
          a11 = __builtin_amdgcn_mfma_f32_32x32x16_bf16(xh[1][kf], bh1, a11, 0, 0, 0);
          a00 = __builtin_amdgcn_mfma_f32_32x32x16_bf16(xh[0][kf], bl0, a00, 0, 0, 0);
          a01 = __builtin_amdgcn_mfma_f32_32x32x16_bf16(xh[0][kf], bl1, a01, 0, 0, 0);
          a10 = __builtin_amdgcn_mfma_f32_32x32x16_bf16(xh[1][kf], bl0, a10, 0, 0, 0);
          a11 = __builtin_amdgcn_mfma_f32_32x32x16_bf16(xh[1][kf], bl1, a11, 0, 0, 0);
          a00 = __builtin_amdgcn_mfma_f32_32x32x16_bf16(xl[0][kf], bh0, a00, 0, 0, 0);
          a01 = __builtin_amdgcn_mfma_f32_32x32x16_bf16(xl[0][kf], bh1, a01, 0, 0, 0);
          a10 = __builtin_amdgcn_mfma_f32_32x32x16_bf16(xl[1][kf], bh0, a10, 0, 0, 0);
          a11 = __builtin_amdgcn_mfma_f32_32x32x16_bf16(xl[1][kf], bh1, a11, 0, 0, 0);
          __builtin_amdgcn_s_setprio(0);
        }
      } else if constexpr (MODE == 4) {
        // pure MFMA: B operands from registers (xh/xl of the other M-tile)
        __builtin_amdgcn_s_setprio(1);
        a00 = __builtin_amdgcn_mfma_f32_32x32x16_bf16(xh[0][kf], xh[1][kf], a00, 0, 0, 0);
        a01 = __builtin_amdgcn_mfma_f32_32x32x16_bf16(xh[0][kf], xl[1][kf], a01, 0, 0, 0);
        a10 = __builtin_amdgcn_mfma_f32_32x32x16_bf16(xh[1][kf], xh[0][kf], a10, 0, 0, 0);
        a11 = __builtin_amdgcn_mfma_f32_32x32x16_bf16(xh[1][kf], xl[0][kf], a11, 0, 0, 0);
        a00 = __builtin_amdgcn_mfma_f32_32x32x16_bf16(xl[0][kf], xh[1][kf], a00, 0, 0, 0);
        a01 = __builtin_amdgcn_mfma_f32_32x32x16_bf16(xl[0][kf], xl[1][kf], a01, 0, 0, 0);
        a10 = __builtin_amdgcn_mfma_f32_32x32x16_bf16(xl[1][kf], xh[0][kf], a10, 0, 0, 0);
        a11 = __builtin_amdgcn_mfma_f32_32x32x16_bf16(xl[1][kf], xl[0][kf], a11, 0, 0, 0);
        a00 = __builtin_amdgcn_mfma_f32_32x32x16_bf16(xh[0][kf], xh[0][kf], a00, 0, 0, 0);
        a01 = __builtin_amdgcn_mfma_f32_32x32x16_bf16(xh[0][kf], xl[0][kf], a01, 0, 0, 0);
        a10 = __builtin_amdgcn_mfma_f32_32x32x16_bf16(xh[1][kf], xh[1][kf], a10, 0, 0, 0);
        a11 = __builtin_amdgcn_mfma_f32_32x32x16_bf16(xh[1][kf], xl[1][kf], a11, 0, 0, 0);
        __builtin_amdgcn_s_setprio(0);
      }
    }
    const unsigned sid0 = (unsigned)(31 - 2 * i);
    const unsigned sid1 = (unsigned)(30 - 2 * i);
#pragma unroll
    for (int r = 0; r < 16; ++r) {
      const unsigned p00 = (__float_as_uint(a00[r]) & 0xFFFFFFE0u) | sid0;
      const unsigned p01 = (__float_as_uint(a01[r]) & 0xFFFFFFE0u) | sid1;
      best[0][r] = fmaxf(best[0][r], fmaxf(__uint_as_float(p00), __uint_as_float(p01)));
      const unsigned p10 = (__float_as_uint(a10[r]) & 0xFFFFFFE0u) | sid0;
      const unsigned p11 = (__float_as_uint(a11[r]) & 0xFFFFFFE0u) | sid1;
      best[1][r] = fmaxf(best[1][r], fmaxf(__uint_as_float(p10), __uint_as_float(p11)));
    }
  }

  unsigned short* qidx =
      (unsigned short*)(ws + (MODE == 0 ? QIDX_OFF : SCR_OFF));
  float ls = 0.f;
#pragma unroll
  for (int m = 0; m < 2; ++m) {
#pragma unroll
    for (int r = 0; r < 16; ++r) {
      float v = best[m][r];
      int idx = (int)(31u - (__float_as_uint(v) & 31u)) * 32 + col;
#pragma unroll
      for (int mk = 1; mk < 32; mk <<= 1) {
        const float ov = __shfl_xor(v, mk);
        const int oi = __shfl_xor(idx, mk);
        if (ov > v || (ov == v && oi < idx)) { v = ov; idx = oi; }
      }
      const int row = (r & 3) + 8 * (r >> 2) + 4 * half;
      if (col == row) {
        const float vc = __uint_as_float(__float_as_uint(v) & 0xFFFFFFE0u);
        ls += xx[m] - 2.0f * vc;
        qidx[blk * 512 + w * 64 + m * 32 + row] = (unsigned short)idx;
      }
    }
  }
#pragma unroll
  for (int mk = 1; mk < 64; mk <<= 1) ls += __shfl_xor(ls, mk);
  if (l == 0)
    atomicAdd(&ws[LOSS_OFF + (MODE == 0 ? 0 : 32) + (blk & (NPART - 1))], ls);
}

__global__ __launch_bounds__(256) void vq_out(
    const float* __restrict__ cb0, const float* __restrict__ cb1,
    float* __restrict__ out, float* __restrict__ ws) {
  const int tid = threadIdx.x;
  const int blk = blockIdx.x;  // 512 blocks x 256 q
  const int bb = blk >> 4;
  const int hw0 = (blk & 15) << 8;
  const int q = bb * 4096 + hw0 + tid;
  const int ci = (int)((const unsigned short*)(ws + QIDX_OFF))[q];
  atomicAdd(ws + PART_OFF + (size_t)(blk & (NPART - 1)) * 1024 + ci, 1.0f);
  const float* crow = (ci < 512) ? (cb0 + (size_t)ci * 64) : (cb1 + (size_t)(ci - 512) * 64);
  float* ob = out + (((size_t)(bb * 64)) << 12) + hw0 + tid;
#pragma unroll
  for (int d4 = 0; d4 < 16; ++d4) {
    const float4 f = *(const float4*)(crow + d4 * 4);
    ob[((size_t)(d4 * 4 + 0)) << 12] = f.x;
    ob[((size_t)(d4 * 4 + 1)) << 12] = f.y;
    ob[((size_t)(d4 * 4 + 2)) << 12] = f.z;
    ob[((size_t)(d4 * 4 + 3)) << 12] = f.w;
  }
}

__global__ void vq_final(const float* __restrict__ ws, float* __restrict__ out) {
  __shared__ float sred[256];
  const int t = threadIdx.x;
  float h = 0.f;
#pragma unroll
  for (int i = t; i < 1024; i += 256) {
    float s = 0.f;
#pragma unroll
    for (int p = 0; p < NPART; ++p) s += ws[PART_OFF + p * 1024 + i];
    const float avg = s * (1.0f / 131072.0f);
    h += avg * logf(avg + 1e-10f);
  }
  sred[t] = h;
  __syncthreads();
  for (int s2 = 128; s2 > 0; s2 >>= 1) {
    if (t < s2) sred[t] += sred[t + s2];
    __syncthreads();
  }
  if (t == 0) {
    float lsum = 0.f;
#pragma unroll
    for (int p = 0; p < NPART; ++p) lsum += ws[LOSS_OFF + p];
    out[8388608] = 1.25f * lsum * (1.0f / 8388608.0f);
    out[8388609] = expf(-sred[0]);
  }
}

extern "C" void kernel_launch(void* const* d_in, const int* in_sizes, int n_in,
                              void* d_out, int out_size, void* d_ws, size_t ws_size,
                              hipStream_t stream) {
  (void)in_sizes; (void)n_in; (void)out_size; (void)ws_size;
  const float* xin = (const float*)d_in[0];
  const float* cb0 = (const float*)d_in[1];
  const float* cb1 = (const float*)d_in[2];
  const int* idxp = (const int*)d_in[3];
  float* out = (float*)d_out;
  float* ws = (float*)d_ws;

  vq_pack<<<4, 256, 0, stream>>>(cb0, cb1, ws);
  vq_dist_t<0><<<256, 512, 0, stream>>>(xin, idxp, ws);
  vq_out<<<512, 256, 0, stream>>>(cb0, cb1, out, ws);
  vq_final<<<1, 256, 0, stream>>>(ws, out);
  // ---- ablation dispatches (scratch outputs; per-dispatch rocprof rows)
  vq_dist_t<1><<<256, 512, 0, stream>>>(xin, idxp, ws);  // noMFMA
  vq_dist_t<2><<<256, 512, 0, stream>>>(xin, idxp, ws);  // noLDSread+noMFMA
  vq_dist_t<3><<<256, 512, 0, stream>>>(xin, idxp, ws);  // noSync (prestaged)
  vq_dist_t<4><<<256, 512, 0, stream>>>(xin, idxp, ws);  // regB (no LDS)
}

// Round 14
// 98.556 us; speedup vs baseline: 2.9186x; 2.9186x over previous
//
#include <hip/hip_runtime.h>

// VQ-VAE vector quantization via bf16-split MFMA (x=xh+xl, c=ch+cl; score =
// xh.ch + xh.cl + xl.ch - 0.5||c||^2, err ~2^-18 relative).
// Round 14: UNPIN the K-loop. Rounds 10-13 had per-sub-phase
// lgkmcnt(0)+sched_barrier(0) (rule-18 discipline that only applies to
// inline-asm ds_reads) -> zero LDS||MFMA overlap -> pipes ran serially
// (ablation: noMFMA ~= full, 74us). This round: no scheduling pins; each
// chunk is a depth-1 register pipeline (load kf+1 fragments while MFMA kf),
// compiler emits counted lgkmcnt. Ring-4 + counted vmcnt (required: GLL has
// no dest reg) + one raw barrier/chunk + nhn-in-LDS kept from round 12.
// ws layout (floats):
//   [0..31]         loss partials
//   [1024..2047]    nhn = -0.5||c||^2
//   [2048..34815]   hist partials 32 x 1024
//   [34816..100351] packed codes: 16 chunks x 4096 floats (16KB):
//                   [16 granules][64 codes][16B]; g<8: hi dims 8g.., g>=8: lo
//   [102400..167935] qidx as ushort[131072]

typedef __attribute__((ext_vector_type(8))) short short8;
typedef __attribute__((ext_vector_type(16))) float f32x16;

#define LOSS_OFF 0
#define NHN_OFF 1024
#define PART_OFF 2048
#define PACKED_OFF 34816
#define QIDX_OFF 102400
#define NPART 32

#define GLL16(gsrc, ldst)                                                      \
  __builtin_amdgcn_global_load_lds(                                            \
      (const __attribute__((address_space(1))) void*)(gsrc),                   \
      (__attribute__((address_space(3))) void*)(ldst), 16, 0, 0)

__device__ __forceinline__ unsigned short bf16_rne(float v, float& rest) {
  const unsigned u = __float_as_uint(v);
  const unsigned r = u + 0x7fffu + ((u >> 16) & 1u);
  const unsigned short h = (unsigned short)(r >> 16);
  rest = v - __uint_as_float((unsigned)h << 16);
  return h;
}

__global__ void vq_pack(const float* __restrict__ cb0, const float* __restrict__ cb1,
                        float* __restrict__ ws) {
  const int c = blockIdx.x * 256 + threadIdx.x;  // 0..1023
  if (c < NPART) ws[LOSS_OFF + c] = 0.0f;
#pragma unroll
  for (int p = 0; p < NPART; ++p) ws[PART_OFF + p * 1024 + c] = 0.0f;
  const float* row = (c < 512) ? (cb0 + (size_t)c * 64) : (cb1 + (size_t)(c - 512) * 64);
  float v[64];
  float nrm = 0.f;
#pragma unroll
  for (int d = 0; d < 64; d += 4) {
    const float4 f = *(const float4*)(row + d);
    v[d] = f.x; v[d + 1] = f.y; v[d + 2] = f.z; v[d + 3] = f.w;
    nrm += f.x * f.x + f.y * f.y + f.z * f.z + f.w * f.w;
  }
  ws[NHN_OFF + c] = -0.5f * nrm;
  unsigned short hi[64], lo[64];
#pragma unroll
  for (int d = 0; d < 64; ++d) {
    float rest, dump;
    hi[d] = bf16_rne(v[d], rest);
    lo[d] = bf16_rne(rest, dump);
  }
  float* base = ws + PACKED_OFF + (size_t)(c >> 6) * 4096 + (c & 63) * 4;
#pragma unroll
  for (int g = 0; g < 16; ++g) {
    short8 gr;
#pragma unroll
    for (int e = 0; e < 8; ++e)
      gr[e] = (short)((g < 8) ? hi[g * 8 + e] : lo[(g - 8) * 8 + e]);
    *(short8*)(base + g * 256) = gr;
  }
}

__global__ __launch_bounds__(512, 2) void vq_dist(
    const float* __restrict__ xin, const int* __restrict__ idxp,
    float* __restrict__ ws) {
  __shared__ char smem[69632];  // 4 x 16KB ring + 4KB nhn
  char* ring = smem;
  float* nhl = (float*)(smem + 65536);
  const int tid = threadIdx.x;
  const int w = tid >> 6;      // wave 0..7, owns q rows w*64..+63
  const int l = tid & 63;
  const int half = l >> 5;
  const int col = l & 31;
  const int blk = blockIdx.x;  // 256 blocks x 512 q
  const int bb = blk >> 3;
  const int hw0 = (blk & 7) << 9;
  const int nch = (*idxp == 0) ? 8 : 16;
  const char* pk = (const char*)(ws + PACKED_OFF);

  // ---- nhn -> LDS (out of the K-loop's vmcnt domain)
  const float nv0 = ws[NHN_OFF + tid];
  const float nv1 = ws[NHN_OFF + 512 + tid];

  // ---- x: direct global->reg, 2 M-tiles (q = w*64 + m*32 + col)
  short8 xh[2][4], xl[2][4];
  float xx[2];
#pragma unroll
  for (int m = 0; m < 2; ++m) {
    float vv[4][8];
    const float* xb =
        xin + ((size_t)(bb * 64 + half * 8)) * 4096 + hw0 + w * 64 + m * 32 + col;
#pragma unroll
    for (int kf = 0; kf < 4; ++kf)
#pragma unroll
      for (int j = 0; j < 8; ++j)
        vv[kf][j] = xb[((size_t)(kf * 16 + j)) * 4096];
    float s = 0.f;
#pragma unroll
    for (int kf = 0; kf < 4; ++kf)
#pragma unroll
      for (int j = 0; j < 8; ++j) {
        const float v = vv[kf][j];
        float rest, dump;
        xh[m][kf][j] = (short)bf16_rne(v, rest);
        xl[m][kf][j] = (short)bf16_rne(rest, dump);
        s += v * v;
      }
    s += __shfl_xor(s, 32);  // lanes l, l^32: same q, complementary dims
    xx[m] = s;
  }
  nhl[tid] = nv0;
  nhl[512 + tid] = nv1;
  __syncthreads();  // nhn LDS visible to all; x loads retired (full drain once)

  // best[m][r]: score with low 5 mantissa bits = (31 - (ch*2+n)); fmax
  // prefers smaller code index on near-ties. <=2^-18 perturbation.
  float best[2][16];
#pragma unroll
  for (int m = 0; m < 2; ++m)
#pragma unroll
    for (int r = 0; r < 16; ++r) best[m][r] = -3.4e38f;

  // stage chunk ch: 16KB over 8 waves -> 2 x 1KB GLL per wave
  auto stage = [&](int ch, int buf) {
    const char* src = pk + (size_t)ch * 16384 + w * 2048 + l * 16;
    char* dst = ring + buf * 16384 + w * 2048;
    GLL16(src, dst);
    GLL16(src + 1024, dst + 1024);
  };

  stage(0, 0);
  stage(1, 1);
  stage(2, 2);  // 6 outstanding per wave
  for (int i = 0; i < nch; ++i) {
    // chunk i's 2 GLLs are the oldest in flight (issued 3 periods back ->
    // pre-satisfied in steady state). Counted vmcnt REQUIRED: GLL has no
    // dest register so the compiler cannot track it.
    if (i < nch - 2) {
      asm volatile("s_waitcnt vmcnt(4)" ::: "memory");
    } else if (i == nch - 2) {
      asm volatile("s_waitcnt vmcnt(2)" ::: "memory");
    } else {
      asm volatile("s_waitcnt vmcnt(0)" ::: "memory");
    }
    __builtin_amdgcn_s_barrier();  // chunk i resident; chunk i-1 consumed
    if (i + 3 < nch) stage(i + 3, (i + 3) & 3);  // refills buf[(i-1)&3]: safe
    const char* bufp = ring + (i & 3) * 16384;
    const int cb = col * 16;
    const float nh0 = nhl[i * 64 + col];
    const float nh1 = nhl[i * 64 + 32 + col];
    f32x16 a00, a01, a10, a11;
#pragma unroll
    for (int r = 0; r < 16; ++r) {
      a00[r] = nh0; a01[r] = nh1; a10[r] = nh0; a11[r] = nh1;
    }
    // depth-1 register pipeline over the 4 sub-phases; NO scheduling pins —
    // pointer-based ds_reads are compiler-tracked (counted lgkmcnt), so
    // sub-phase kf+1's reads issue under kf's MFMA burst.
    short8 ch0, ch1, cl0, cl1, nx0, nx1, nx2, nx3;
    {
      const char* ph = bufp + (half)*1024 + cb;
      const char* pl = bufp + (8 + half) * 1024 + cb;
      ch0 = *(const short8*)(ph);
      ch1 = *(const short8*)(ph + 512);
      cl0 = *(const short8*)(pl);
      cl1 = *(const short8*)(pl + 512);
    }
#pragma unroll
    for (int kf = 0; kf < 4; ++kf) {
      if (kf < 3) {
        const char* ph = bufp + (2 * (kf + 1) + half) * 1024 + cb;
        const char* pl = bufp + (8 + 2 * (kf + 1) + half) * 1024 + cb;
        nx0 = *(const short8*)(ph);
        nx1 = *(const short8*)(ph + 512);
        nx2 = *(const short8*)(pl);
        nx3 = *(const short8*)(pl + 512);
      }
      __builtin_amdgcn_s_setprio(1);
      a00 = __builtin_amdgcn_mfma_f32_32x32x16_bf16(xh[0][kf], ch0, a00, 0, 0, 0);
      a01 = __builtin_amdgcn_mfma_f32_32x32x16_bf16(xh[0][kf], ch1, a01, 0, 0, 0);
      a10 = __builtin_amdgcn_mfma_f32_32x32x16_bf16(xh[1][kf], ch0, a10, 0, 0, 0);
      a11 = __builtin_amdgcn_mfma_f32_32x32x16_bf16(xh[1][kf], ch1, a11, 0, 0, 0);
      a00 = __builtin_amdgcn_mfma_f32_32x32x16_bf16(xh[0][kf], cl0, a00, 0, 0, 0);
      a01 = __builtin_amdgcn_mfma_f32_32x32x16_bf16(xh[0][kf], cl1, a01, 0, 0, 0);
      a10 = __builtin_amdgcn_mfma_f32_32x32x16_bf16(xh[1][kf], cl0, a10, 0, 0, 0);
      a11 = __builtin_amdgcn_mfma_f32_32x32x16_bf16(xh[1][kf], cl1, a11, 0, 0, 0);
      a00 = __builtin_amdgcn_mfma_f32_32x32x16_bf16(xl[0][kf], ch0, a00, 0, 0, 0);
      a01 = __builtin_amdgcn_mfma_f32_32x32x16_bf16(xl[0][kf], ch1, a01, 0, 0, 0);
      a10 = __builtin_amdgcn_mfma_f32_32x32x16_bf16(xl[1][kf], ch0, a10, 0, 0, 0);
      a11 = __builtin_amdgcn_mfma_f32_32x32x16_bf16(xl[1][kf], ch1, a11, 0, 0, 0);
      __builtin_amdgcn_s_setprio(0);
      ch0 = nx0; ch1 = nx1; cl0 = nx2; cl1 = nx3;  // SSA renames, no moves
    }
    const unsigned sid0 = (unsigned)(31 - 2 * i);
    const unsigned sid1 = (unsigned)(30 - 2 * i);
#pragma unroll
    for (int r = 0; r < 16; ++r) {
      const unsigned p00 = (__float_as_uint(a00[r]) & 0xFFFFFFE0u) | sid0;
      const unsigned p01 = (__float_as_uint(a01[r]) & 0xFFFFFFE0u) | sid1;
      best[0][r] = fmaxf(best[0][r], fmaxf(__uint_as_float(p00), __uint_as_float(p01)));
      const unsigned p10 = (__float_as_uint(a10[r]) & 0xFFFFFFE0u) | sid0;
      const unsigned p11 = (__float_as_uint(a11[r]) & 0xFFFFFFE0u) | sid1;
      best[1][r] = fmaxf(best[1][r], fmaxf(__uint_as_float(p10), __uint_as_float(p11)));
    }
  }

  // ---- cross-lane argmax reduce (within 32-lane half), first-index ties
  unsigned short* qidx = (unsigned short*)(ws + QIDX_OFF);
  float ls = 0.f;
#pragma unroll
  for (int m = 0; m < 2; ++m) {
#pragma unroll
    for (int r = 0; r < 16; ++r) {
      float v = best[m][r];
      int idx = (int)(31u - (__float_as_uint(v) & 31u)) * 32 + col;
#pragma unroll
      for (int mk = 1; mk < 32; mk <<= 1) {
        const float ov = __shfl_xor(v, mk);
        const int oi = __shfl_xor(idx, mk);
        if (ov > v || (ov == v && oi < idx)) { v = ov; idx = oi; }
      }
      const int row = (r & 3) + 8 * (r >> 2) + 4 * half;  // C layout row
      if (col == row) {
        const float vc = __uint_as_float(__float_as_uint(v) & 0xFFFFFFE0u);
        ls += xx[m] - 2.0f * vc;  // ||x||^2 - 2(x.c* - 0.5||c*||^2)
        qidx[blk * 512 + w * 64 + m * 32 + row] = (unsigned short)idx;
      }
    }
  }
#pragma unroll
  for (int mk = 1; mk < 64; mk <<= 1) ls += __shfl_xor(ls, mk);
  if (l == 0) atomicAdd(&ws[LOSS_OFF + (blk & (NPART - 1))], ls);
}

__global__ __launch_bounds__(256) void vq_out(
    const float* __restrict__ cb0, const float* __restrict__ cb1,
    float* __restrict__ out, float* __restrict__ ws) {
  const int tid = threadIdx.x;
  const int blk = blockIdx.x;  // 512 blocks x 256 q
  const int bb = blk >> 4;
  const int hw0 = (blk & 15) << 8;
  const int q = bb * 4096 + hw0 + tid;
  const int ci = (int)((const unsigned short*)(ws + QIDX_OFF))[q];
  atomicAdd(ws + PART_OFF + (size_t)(blk & (NPART - 1)) * 1024 + ci, 1.0f);
  const float* crow = (ci < 512) ? (cb0 + (size_t)ci * 64) : (cb1 + (size_t)(ci - 512) * 64);
  float* ob = out + (((size_t)(bb * 64)) << 12) + hw0 + tid;
#pragma unroll
  for (int d4 = 0; d4 < 16; ++d4) {
    const float4 f = *(const float4*)(crow + d4 * 4);
    ob[((size_t)(d4 * 4 + 0)) << 12] = f.x;
    ob[((size_t)(d4 * 4 + 1)) << 12] = f.y;
    ob[((size_t)(d4 * 4 + 2)) << 12] = f.z;
    ob[((size_t)(d4 * 4 + 3)) << 12] = f.w;
  }
}

__global__ void vq_final(const float* __restrict__ ws, float* __restrict__ out) {
  __shared__ float sred[256];
  const int t = threadIdx.x;
  float h = 0.f;
#pragma unroll
  for (int i = t; i < 1024; i += 256) {
    float s = 0.f;
#pragma unroll
    for (int p = 0; p < NPART; ++p) s += ws[PART_OFF + p * 1024 + i];
    const float avg = s * (1.0f / 131072.0f);
    h += avg * logf(avg + 1e-10f);
  }
  sred[t] = h;
  __syncthreads();
  for (int s2 = 128; s2 > 0; s2 >>= 1) {
    if (t < s2) sred[t] += sred[t + s2];
    __syncthreads();
  }
  if (t == 0) {
    float lsum = 0.f;
#pragma unroll
    for (int p = 0; p < NPART; ++p) lsum += ws[LOSS_OFF + p];
    out[8388608] = 1.25f * lsum * (1.0f / 8388608.0f);
    out[8388609] = expf(-sred[0]);
  }
}

extern "C" void kernel_launch(void* const* d_in, const int* in_sizes, int n_in,
                              void* d_out, int out_size, void* d_ws, size_t ws_size,
                              hipStream_t stream) {
  (void)in_sizes; (void)n_in; (void)out_size; (void)ws_size;
  const float* xin = (const float*)d_in[0];
  const float* cb0 = (const float*)d_in[1];
  const float* cb1 = (const float*)d_in[2];
  const int* idxp = (const int*)d_in[3];
  float* out = (float*)d_out;
  float* ws = (float*)d_ws;

  vq_pack<<<4, 256, 0, stream>>>(cb0, cb1, ws);
  vq_dist<<<256, 512, 0, stream>>>(xin, idxp, ws);
  vq_out<<<512, 256, 0, stream>>>(cb0, cb1, out, ws);
  vq_final<<<1, 256, 0, stream>>>(ws, out);
}

// Round 15
// 84.826 us; speedup vs baseline: 3.3910x; 1.1619x over previous
//
#include <hip/hip_runtime.h>

// VQ-VAE vector quantization via bf16-split MFMA, SWAPPED operands:
// A = codes (LDS), B = x (regs) -> C[row=code][col=q]: each lane owns ONE
// query => argmax is lane-local (no 32-lane butterfly, no divergent writes).
// score = c~.x~ : 3 bf16 terms (ch.xh + ch.xl + cl.xh) + nh-granule MFMA
// (granule 16/17 = 3-term bf16 split of -0.5||c||^2 times x~=[1,1,1]) with a
// persistent ZERO as C-in (no per-chunk acc init, no nh loads/adds).
// Round 15. Ring-3 x 24KB, 6 GLL/wave/chunk, counted vmcnt(6), 1 barrier/chunk.
// ws layout (floats):
//   [0..31]          loss partials
//   [2048..34815]    hist partials 32 x 1024
//   [34816..133119]  packed codes: 16 chunks x 6144 floats (24KB):
//                    [24 granules][64 codes][16B]; g0-7 hi, g8-15 lo,
//                    g16 = [nh0,nh1,nh2,0...], g17 = zeros, g18-23 pad
//   [133120..198655] qidx as ushort[131072]

typedef __attribute__((ext_vector_type(8))) short short8;
typedef __attribute__((ext_vector_type(16))) float f32x16;

#define LOSS_OFF 0
#define PART_OFF 2048
#define PACKED_OFF 34816
#define QIDX_OFF 133120
#define NPART 32
#define CHUNK_B 24576

#define GLL16(gsrc, ldst)                                                      \
  __builtin_amdgcn_global_load_lds(                                            \
      (const __attribute__((address_space(1))) void*)(gsrc),                   \
      (__attribute__((address_space(3))) void*)(ldst), 16, 0, 0)

__device__ __forceinline__ unsigned short bf16_rne(float v, float& rest) {
  const unsigned u = __float_as_uint(v);
  const unsigned r = u + 0x7fffu + ((u >> 16) & 1u);
  const unsigned short h = (unsigned short)(r >> 16);
  rest = v - __uint_as_float((unsigned)h << 16);
  return h;
}

__global__ void vq_pack(const float* __restrict__ cb0, const float* __restrict__ cb1,
                        float* __restrict__ ws) {
  const int c = blockIdx.x * 256 + threadIdx.x;  // 0..1023
  if (c < NPART) ws[LOSS_OFF + c] = 0.0f;
#pragma unroll
  for (int p = 0; p < NPART; ++p) ws[PART_OFF + p * 1024 + c] = 0.0f;
  const float* row = (c < 512) ? (cb0 + (size_t)c * 64) : (cb1 + (size_t)(c - 512) * 64);
  float v[64];
  float nrm = 0.f;
#pragma unroll
  for (int d = 0; d < 64; d += 4) {
    const float4 f = *(const float4*)(row + d);
    v[d] = f.x; v[d + 1] = f.y; v[d + 2] = f.z; v[d + 3] = f.w;
    nrm += f.x * f.x + f.y * f.y + f.z * f.z + f.w * f.w;
  }
  unsigned short hi[64], lo[64];
#pragma unroll
  for (int d = 0; d < 64; ++d) {
    float rest, dump;
    hi[d] = bf16_rne(v[d], rest);
    lo[d] = bf16_rne(rest, dump);
  }
  float* base = ws + PACKED_OFF + (size_t)(c >> 6) * 6144 + (c & 63) * 4;
#pragma unroll
  for (int g = 0; g < 16; ++g) {
    short8 gr;
#pragma unroll
    for (int e = 0; e < 8; ++e)
      gr[e] = (short)((g < 8) ? hi[g * 8 + e] : lo[(g - 8) * 8 + e]);
    *(short8*)(base + g * 256) = gr;
  }
  {  // g16 = 3-term bf16 split of -0.5||c||^2 ; g17 = zeros (half-1 k-slice)
    const float nh = -0.5f * nrm;
    float r1, r2, dump;
    const unsigned short n0 = bf16_rne(nh, r1);
    const unsigned short n1 = bf16_rne(r1, r2);
    const unsigned short n2 = bf16_rne(r2, dump);
    short8 g16 = {(short)n0, (short)n1, (short)n2, 0, 0, 0, 0, 0};
    *(short8*)(base + 16 * 256) = g16;
    short8 zz = {0, 0, 0, 0, 0, 0, 0, 0};
    *(short8*)(base + 17 * 256) = zz;
  }
}

__global__ __launch_bounds__(256, 2) void vq_dist(
    const float* __restrict__ xin, const int* __restrict__ idxp,
    float* __restrict__ ws) {
  __shared__ char ring[73728];  // 3 x 24KB ring (only LDS use)
  const int tid = threadIdx.x;
  const int w = tid >> 6;      // wave 0..3, owns q w*64..+63
  const int l = tid & 63;
  const int half = l >> 5;
  const int col = l & 31;      // = this lane's q within its 32-col tile
  const int blk = blockIdx.x;  // 512 blocks x 256 q
  const int bb = blk >> 4;
  const int hw0 = (blk & 15) << 8;
  const int nch = (*idxp == 0) ? 8 : 16;
  const char* pk = (const char*)(ws + PACKED_OFF);

  // ---- x: direct global->reg, B-fragments for 2 q-col-tiles
  short8 xh[2][4], xl[2][4];
  float xx[2];
#pragma unroll
  for (int m = 0; m < 2; ++m) {
    float vv[4][8];
    const float* xb =
        xin + ((size_t)(bb * 64 + half * 8)) * 4096 + hw0 + w * 64 + m * 32 + col;
#pragma unroll
    for (int kf = 0; kf < 4; ++kf)
#pragma unroll
      for (int j = 0; j < 8; ++j)
        vv[kf][j] = xb[((size_t)(kf * 16 + j)) * 4096];
    float s = 0.f;
#pragma unroll
    for (int kf = 0; kf < 4; ++kf)
#pragma unroll
      for (int j = 0; j < 8; ++j) {
        const float v = vv[kf][j];
        float rest, dump;
        xh[m][kf][j] = (short)bf16_rne(v, rest);
        xl[m][kf][j] = (short)bf16_rne(rest, dump);
        s += v * v;
      }
    s += __shfl_xor(s, 32);  // lanes l, l^32: same q, complementary dims
    xx[m] = s;
  }
  // x~ extension fragment for the nh-granule MFMA: k=0..2 = 1.0 (half-0)
  short8 xnh;
#pragma unroll
  for (int j = 0; j < 8; ++j)
    xnh[j] = (short)((half == 0 && j < 3) ? 0x3F80 : 0);
  const f32x16 ZV = (f32x16)0.0f;  // persistent zero C-input
  asm volatile("s_waitcnt vmcnt(0)" ::: "memory");  // x retired: clean count

  // best[m][r]: packed score, low 5 mantissa bits = 31-(2*chunk+n); fmax
  // prefers smaller code on near-ties; r identity kept by register position.
  float best[2][16];
#pragma unroll
  for (int m = 0; m < 2; ++m)
#pragma unroll
    for (int r = 0; r < 16; ++r) best[m][r] = -3.4e38f;

  // stage chunk: 24KB over 4 waves -> 6 x 1KB GLL per wave
  auto stage = [&](int ch, int buf) {
    const char* src = pk + (size_t)ch * CHUNK_B + w * 6144 + l * 16;
    char* dst = ring + buf * CHUNK_B + w * 6144;
#pragma unroll
    for (int i = 0; i < 6; ++i) GLL16(src + i * 1024, dst + i * 1024);
  };

  stage(0, 0);
  stage(1, 1);  // 12 outstanding per wave
  for (int i = 0; i < nch; ++i) {
    if (i < nch - 1) {
      asm volatile("s_waitcnt vmcnt(6)" ::: "memory");  // chunk i landed
    } else {
      asm volatile("s_waitcnt vmcnt(0)" ::: "memory");
    }
    __builtin_amdgcn_s_barrier();  // chunk i resident; chunk i-1 consumed
    if (i + 2 < nch) stage(i + 2, (i + 2) % 3);  // refills buf[(i-1)%3]: safe
    const char* bufp = ring + (i % 3) * CHUNK_B;
    const char* tb0 = bufp + col * 16;          // n=0 code tile, row = col
    const char* tb1 = bufp + (32 + col) * 16;   // n=1 code tile

    // nh-granule MFMAs initialize the accumulators (C = ZV)
    const short8 An0 = *(const short8*)(tb0 + (16 + half) * 1024);
    const short8 An1 = *(const short8*)(tb1 + (16 + half) * 1024);
    f32x16 a00 = __builtin_amdgcn_mfma_f32_32x32x16_bf16(An0, xnh, ZV, 0, 0, 0);
    f32x16 a01 = __builtin_amdgcn_mfma_f32_32x32x16_bf16(An1, xnh, ZV, 0, 0, 0);
    f32x16 a10 = __builtin_amdgcn_mfma_f32_32x32x16_bf16(An0, xnh, ZV, 0, 0, 0);
    f32x16 a11 = __builtin_amdgcn_mfma_f32_32x32x16_bf16(An1, xnh, ZV, 0, 0, 0);
#pragma unroll
    for (int kf = 0; kf < 4; ++kf) {
      const short8 Ah0 = *(const short8*)(tb0 + (2 * kf + half) * 1024);
      const short8 Ah1 = *(const short8*)(tb1 + (2 * kf + half) * 1024);
      const short8 Al0 = *(const short8*)(tb0 + (8 + 2 * kf + half) * 1024);
      const short8 Al1 = *(const short8*)(tb1 + (8 + 2 * kf + half) * 1024);
      a00 = __builtin_amdgcn_mfma_f32_32x32x16_bf16(Ah0, xh[0][kf], a00, 0, 0, 0);
      a01 = __builtin_amdgcn_mfma_f32_32x32x16_bf16(Ah1, xh[0][kf], a01, 0, 0, 0);
      a10 = __builtin_amdgcn_mfma_f32_32x32x16_bf16(Ah0, xh[1][kf], a10, 0, 0, 0);
      a11 = __builtin_amdgcn_mfma_f32_32x32x16_bf16(Ah1, xh[1][kf], a11, 0, 0, 0);
      a00 = __builtin_amdgcn_mfma_f32_32x32x16_bf16(Ah0, xl[0][kf], a00, 0, 0, 0);
      a01 = __builtin_amdgcn_mfma_f32_32x32x16_bf16(Ah1, xl[0][kf], a01, 0, 0, 0);
      a10 = __builtin_amdgcn_mfma_f32_32x32x16_bf16(Ah0, xl[1][kf], a10, 0, 0, 0);
      a11 = __builtin_amdgcn_mfma_f32_32x32x16_bf16(Ah1, xl[1][kf], a11, 0, 0, 0);
      a00 = __builtin_amdgcn_mfma_f32_32x32x16_bf16(Al0, xh[0][kf], a00, 0, 0, 0);
      a01 = __builtin_amdgcn_mfma_f32_32x32x16_bf16(Al1, xh[0][kf], a01, 0, 0, 0);
      a10 = __builtin_amdgcn_mfma_f32_32x32x16_bf16(Al0, xh[1][kf], a10, 0, 0, 0);
      a11 = __builtin_amdgcn_mfma_f32_32x32x16_bf16(Al1, xh[1][kf], a11, 0, 0, 0);
    }

    // ---- lane-local running argmax (codes on rows -> per-lane regs)
    const unsigned sid0 = (unsigned)(31 - 2 * i);
    const unsigned sid1 = (unsigned)(30 - 2 * i);
#pragma unroll
    for (int r = 0; r < 16; ++r) {
      const float p00 = __uint_as_float((__float_as_uint(a00[r]) & 0xFFFFFFE0u) | sid0);
      const float p01 = __uint_as_float((__float_as_uint(a01[r]) & 0xFFFFFFE0u) | sid1);
      best[0][r] = fmaxf(fmaxf(p00, p01), best[0][r]);
      const float p10 = __uint_as_float((__float_as_uint(a10[r]) & 0xFFFFFFE0u) | sid0);
      const float p11 = __uint_as_float((__float_as_uint(a11[r]) & 0xFFFFFFE0u) | sid1);
      best[1][r] = fmaxf(fmaxf(p10, p11), best[1][r]);
    }
  }

  // ---- epilogue: per-lane reduce over 16 regs + one cross-half exchange
  unsigned short* qidx = (unsigned short*)(ws + QIDX_OFF);
  float ls = 0.f;
#pragma unroll
  for (int m = 0; m < 2; ++m) {
    float win = best[m][0];
    int wr = 0;
#pragma unroll
    for (int r = 1; r < 16; ++r) {
      const bool g = best[m][r] > win;  // tie -> keep lower r (smaller row)
      win = g ? best[m][r] : win;
      wr = g ? r : wr;
    }
    const unsigned u = __float_as_uint(win);
    const int t = 31 - (int)(u & 31u);
    int code = (t >> 1) * 64 + (t & 1) * 32 + ((wr & 3) + 8 * (wr >> 2) + 4 * half);
    float clean = __uint_as_float(u & 0xFFFFFFE0u);
    const float ocl = __shfl_xor(clean, 32);
    const int oc = __shfl_xor(code, 32);
    const bool take = (ocl > clean) || (ocl == clean && oc < code);
    clean = take ? ocl : clean;
    code = take ? oc : code;
    if (half == 0) {
      qidx[bb * 4096 + hw0 + w * 64 + m * 32 + col] = (unsigned short)code;
      ls += xx[m] - 2.0f * clean;  // ||x||^2 - 2(x.c* - 0.5||c*||^2)
    }
  }
#pragma unroll
  for (int mk = 1; mk < 64; mk <<= 1) ls += __shfl_xor(ls, mk);
  if (l == 0) atomicAdd(&ws[LOSS_OFF + (blk & (NPART - 1))], ls);
}

__global__ __launch_bounds__(256) void vq_out(
    const float* __restrict__ cb0, const float* __restrict__ cb1,
    float* __restrict__ out, float* __restrict__ ws) {
  const int tid = threadIdx.x;
  const int blk = blockIdx.x;  // 512 blocks x 256 q
  const int bb = blk >> 4;
  const int hw0 = (blk & 15) << 8;
  const int q = bb * 4096 + hw0 + tid;
  const int ci = (int)((const unsigned short*)(ws + QIDX_OFF))[q];
  atomicAdd(ws + PART_OFF + (size_t)(blk & (NPART - 1)) * 1024 + ci, 1.0f);
  const float* crow = (ci < 512) ? (cb0 + (size_t)ci * 64) : (cb1 + (size_t)(ci - 512) * 64);
  float* ob = out + (((size_t)(bb * 64)) << 12) + hw0 + tid;
#pragma unroll
  for (int d4 = 0; d4 < 16; ++d4) {
    const float4 f = *(const float4*)(crow + d4 * 4);
    ob[((size_t)(d4 * 4 + 0)) << 12] = f.x;
    ob[((size_t)(d4 * 4 + 1)) << 12] = f.y;
    ob[((size_t)(d4 * 4 + 2)) << 12] = f.z;
    ob[((size_t)(d4 * 4 + 3)) << 12] = f.w;
  }
}

__global__ void vq_final(const float* __restrict__ ws, float* __restrict__ out) {
  __shared__ float sred[256];
  const int t = threadIdx.x;
  float h = 0.f;
#pragma unroll
  for (int i = t; i < 1024; i += 256) {
    float s = 0.f;
#pragma unroll
    for (int p = 0; p < NPART; ++p) s += ws[PART_OFF + p * 1024 + i];
    const float avg = s * (1.0f / 131072.0f);
    h += avg * logf(avg + 1e-10f);
  }
  sred[t] = h;
  __syncthreads();
  for (int s2 = 128; s2 > 0; s2 >>= 1) {
    if (t < s2) sred[t] += sred[t + s2];
    __syncthreads();
  }
  if (t == 0) {
    float lsum = 0.f;
#pragma unroll
    for (int p = 0; p < NPART; ++p) lsum += ws[LOSS_OFF + p];
    out[8388608] = 1.25f * lsum * (1.0f / 8388608.0f);
    out[8388609] = expf(-sred[0]);
  }
}

extern "C" void kernel_launch(void* const* d_in, const int* in_sizes, int n_in,
                              void* d_out, int out_size, void* d_ws, size_t ws_size,
                              hipStream_t stream) {
  (void)in_sizes; (void)n_in; (void)out_size; (void)ws_size;
  const float* xin = (const float*)d_in[0];
  const float* cb0 = (const float*)d_in[1];
  const float* cb1 = (const float*)d_in[2];
  const int* idxp = (const int*)d_in[3];
  float* out = (float*)d_out;
  float* ws = (float*)d_ws;

  vq_pack<<<4, 256, 0, stream>>>(cb0, cb1, ws);
  vq_dist<<<512, 256, 0, stream>>>(xin, idxp, ws);
  vq_out<<<512, 256, 0, stream>>>(cb0, cb1, out, ws);
  vq_final<<<1, 256, 0, stream>>>(ws, out);
}